// Round 7
// baseline (54.126 us; speedup 1.0000x reference)
//
#include <hip/hip_runtime.h>

// RPNPooling: B=2, H=128, W=128, C=256, N=512, POOL=14
// out[q,i,j,ch], q in [0,1024), i,j in [0,14), ch in [0,256)
// Reference quirk: r-axis (feature H index) derives from roi x-coords,
// c-axis (feature W index) derives from roi y-coords. Replicated verbatim.
//
// R6 = R5 with ONE change: plain cached stores instead of nontemporal
// (single-variable A/B; all three prior structures used NT and converged
// at ~51 us, so the store path is the last untested variable).

typedef float f32x4 __attribute__((ext_vector_type(4)));

#define NROI 1024
#define WAVES_TOTAL (NROI * 14)      // 14336
#define THREADS 256                  // 4 waves/block
#define NBLK (WAVES_TOTAL / 4)       // 3584, % 8 == 0

__global__ __launch_bounds__(THREADS) void rpn_pool_kernel(
    const float* __restrict__ feat,   // [2,128,128,256]
    const int*   __restrict__ roi,    // [1024,4] = y1,x1,y2,x2
    float*       __restrict__ out)    // [1024,14,14,256]
{
    const int lane = threadIdx.x & 63;
    const int wv   = threadIdx.x >> 6;

    // XCD chunking (bijective, 3584 % 8 == 0): XCD k owns 128 whole ROIs.
    const int d   = blockIdx.x;
    const int blk = (d & 7) * (NBLK / 8) + (d >> 3);
    const int W   = blk * 4 + wv;     // wave id in [0, 14336)
    const int q   = W / 14;
    const int j   = W - q * 14;
    const int b   = q >> 9;

    const int4 rr = ((const int4*)roi)[q];
    const int y1 = rr.x, x1 = rr.y, y2 = rr.z, x2 = rr.w;
    const int sR = x2 - x1;           // H-extent from x coords (reference swap)
    const int sC = y2 - y1;           // W-extent from y coords

    // Column constants for this wave
    const int pc  = j * sC;
    const int ic0 = pc / 14;
    const float fc  = (float)(pc - ic0 * 14) * (1.0f / 14.0f);
    const float wc1 = 1.0f - fc;
    const int c0 = ic0;
    const int c1 = min(ic0 + 1, sC - 1);

    const size_t SB4 = (size_t)128 * 128 * 64;   // f32x4 strides
    const size_t SR4 = (size_t)128 * 64;
    const f32x4* base = (const f32x4*)feat + (size_t)b * SB4
                        + (size_t)x1 * SR4 + (size_t)y1 * 64 + lane;
    const size_t o0 = (size_t)c0 * 64, o1 = (size_t)c1 * 64;

    // Prologue: rows 0 and rB=min(1,sR-1)  (sR >= 8 so rB = 1)
    int rA = 0, rB = min(1, sR - 1);
    f32x4 a0 = base[o0];
    f32x4 a1 = base[o1];
    f32x4 b0 = base[(size_t)rB * SR4 + o0];
    f32x4 b1 = base[(size_t)rB * SR4 + o1];

    f32x4* outp = (f32x4*)out + ((size_t)q * 196 + j) * 64 + lane;

    for (int i = 0; i < 14; ++i) {
        const int pr = i * sR;                    // rA == pr/14 (invariant)
        const float fr = (float)(pr - rA * 14) * (1.0f / 14.0f);

        // Prefetch next step's new row (wave-uniform branch).
        int nA = rA, nB = rB;
        f32x4 p0, p1;
        bool adv = false;
        if (i < 13) {
            nA = ((i + 1) * sR) / 14;
            nB = min(nA + 1, sR - 1);
            if (nB > rB) {
                p0 = base[(size_t)nB * SR4 + o0];
                p1 = base[(size_t)nB * SR4 + o1];
                adv = true;
            }
        }

        f32x4 o = (a0 * wc1 + a1 * fc) * (1.0f - fr) + (b0 * wc1 + b1 * fc) * fr;
        outp[(size_t)i * 14 * 64] = o;            // plain cached store (A/B vs NT)

        if (nA > rA) { a0 = b0; a1 = b1; }        // adv => nA > rA; coherent
        if (adv)     { b0 = p0; b1 = p1; }
        rA = nA; rB = nB;
    }
}

extern "C" void kernel_launch(void* const* d_in, const int* in_sizes, int n_in,
                              void* d_out, int out_size, void* d_ws, size_t ws_size,
                              hipStream_t stream) {
    const float* feat = (const float*)d_in[0];
    const int*   roi  = (const int*)d_in[1];
    float* out = (float*)d_out;

    rpn_pool_kernel<<<NBLK, THREADS, 0, stream>>>(feat, roi, out);
}

// Round 8
// 50.325 us; speedup vs baseline: 1.0755x; 1.0755x over previous
//
#include <hip/hip_runtime.h>

// RPNPooling: B=2, H=128, W=128, C=256, N=512, POOL=14
// out[q,i,j,ch], q in [0,1024), i,j in [0,14), ch in [0,256)
// Reference quirk: r-axis (feature H index) derives from roi x-coords,
// c-axis (feature W index) derives from roi y-coords. Replicated verbatim.
//
// R7 = R5 (register-rolling, wave-per-(q,j)) with ONE change: the output
// store is an inline-asm global_store_dwordx4 with sc0 sc1 nt — the full
// streaming-store policy (builtin NT only sets nt). Hypothesis: the 205 MB
// write stream write-allocates in L2/L3 and thrashes the 33.5 MB feature
// map out of cache (~150 MB extra HBM fetch); scope-bypass stores leave
// L2/L3 to the features.

typedef float f32x4 __attribute__((ext_vector_type(4)));

#define NROI 1024
#define WAVES_TOTAL (NROI * 14)      // 14336
#define THREADS 256                  // 4 waves/block
#define NBLK (WAVES_TOTAL / 4)       // 3584, % 8 == 0

__global__ __launch_bounds__(THREADS) void rpn_pool_kernel(
    const float* __restrict__ feat,   // [2,128,128,256]
    const int*   __restrict__ roi,    // [1024,4] = y1,x1,y2,x2
    float*       __restrict__ out)    // [1024,14,14,256]
{
    const int lane = threadIdx.x & 63;
    const int wv   = threadIdx.x >> 6;

    // XCD chunking (bijective, 3584 % 8 == 0): XCD k owns 128 whole ROIs.
    const int d   = blockIdx.x;
    const int blk = (d & 7) * (NBLK / 8) + (d >> 3);
    const int W   = blk * 4 + wv;     // wave id in [0, 14336)
    const int q   = W / 14;
    const int j   = W - q * 14;
    const int b   = q >> 9;

    const int4 rr = ((const int4*)roi)[q];
    const int y1 = rr.x, x1 = rr.y, y2 = rr.z, x2 = rr.w;
    const int sR = x2 - x1;           // H-extent from x coords (reference swap)
    const int sC = y2 - y1;           // W-extent from y coords

    // Column constants for this wave
    const int pc  = j * sC;
    const int ic0 = pc / 14;
    const float fc  = (float)(pc - ic0 * 14) * (1.0f / 14.0f);
    const float wc1 = 1.0f - fc;
    const int c0 = ic0;
    const int c1 = min(ic0 + 1, sC - 1);

    const size_t SB4 = (size_t)128 * 128 * 64;   // f32x4 strides
    const size_t SR4 = (size_t)128 * 64;
    const f32x4* base = (const f32x4*)feat + (size_t)b * SB4
                        + (size_t)x1 * SR4 + (size_t)y1 * 64 + lane;
    const size_t o0 = (size_t)c0 * 64, o1 = (size_t)c1 * 64;

    // Prologue: rows 0 and rB=min(1,sR-1)  (sR >= 8 so rB = 1)
    int rA = 0, rB = min(1, sR - 1);
    f32x4 a0 = base[o0];
    f32x4 a1 = base[o1];
    f32x4 b0 = base[(size_t)rB * SR4 + o0];
    f32x4 b1 = base[(size_t)rB * SR4 + o1];

    f32x4* outp = (f32x4*)out + ((size_t)q * 196 + j) * 64 + lane;

    for (int i = 0; i < 14; ++i) {
        const int pr = i * sR;                    // rA == pr/14 (invariant)
        const float fr = (float)(pr - rA * 14) * (1.0f / 14.0f);

        // Prefetch next step's new row (wave-uniform branch).
        int nA = rA, nB = rB;
        f32x4 p0, p1;
        bool adv = false;
        if (i < 13) {
            nA = ((i + 1) * sR) / 14;
            nB = min(nA + 1, sR - 1);
            if (nB > rB) {
                p0 = base[(size_t)nB * SR4 + o0];
                p1 = base[(size_t)nB * SR4 + o1];
                adv = true;
            }
        }

        f32x4 o = (a0 * wc1 + a1 * fc) * (1.0f - fr) + (b0 * wc1 + b1 * fc) * fr;

        // Streaming store: bypass L0/L2 allocation, non-temporal in MALL.
        f32x4* p = outp + (size_t)i * 14 * 64;
        asm volatile("global_store_dwordx4 %0, %1, off sc0 sc1 nt"
                     :: "v"(p), "v"(o) : "memory");

        if (nA > rA) { a0 = b0; a1 = b1; }        // adv => nA > rA; coherent
        if (adv)     { b0 = p0; b1 = p1; }
        rA = nA; rB = nB;
    }
}

extern "C" void kernel_launch(void* const* d_in, const int* in_sizes, int n_in,
                              void* d_out, int out_size, void* d_ws, size_t ws_size,
                              hipStream_t stream) {
    const float* feat = (const float*)d_in[0];
    const int*   roi  = (const int*)d_in[1];
    float* out = (float*)d_out;

    rpn_pool_kernel<<<NBLK, THREADS, 0, stream>>>(feat, roi, out);
}